// Round 4
// baseline (21.105 us; speedup 1.0000x reference)
//
#include <hip/hip_runtime.h>

// DendSN: dendritic spiking neuron forward.
// x_seq: (T=8, N=16, C=128, H=32, W=32) fp32 ; k: (1,4,1) fp32
// out:   (T=8, N=16, K=32, H=32, W=32) fp32 (0/1 spikes)
//
// R4: full compartment split — b = lane>>4, one float4 load per thread per
// timestep, ~40 VGPR -> __launch_bounds__(256,8) caps at 64 VGPR = 32
// waves/CU (2x R2's 16). Dendritic sum via shfl_xor(16)+shfl_xor(32),
// same (f0+f1)+(f2+f3) tree R2 validated bit-exactly. LIF redundant in all
// four b-lanes; b==0 lanes store.

#define TT 8
#define NB 16
#define CC 128
#define BB 4
#define KK 32
#define LL 1024   // H*W

__global__ __launch_bounds__(256, 8) void dendsn_fwd(
    const float* __restrict__ x, const float* __restrict__ k,
    float* __restrict__ out)
{
    const int tid  = threadIdx.x;
    const int lane = tid & 63;
    const int b    = lane >> 4;          // compartment 0..3
    const int slot = lane & 15;          // site-group within wave

    // global site4 index: one per (n, kk, l4) spatial 4-group
    const int w     = (blockIdx.x * 256 + tid) >> 6;   // wave id [0, 8192)
    const int site4 = w * 16 + slot;                   // [0, 131072)
    const int l4 = site4 & 255;
    const int kk = (site4 >> 8) & 31;
    const int n  = site4 >> 13;

    // softmax over the 4 dendritic-strength params, folded with the *3.0
    const float k0 = k[0], k1 = k[1], k2 = k[2], k3 = k[3];
    const float m  = fmaxf(fmaxf(k0, k1), fmaxf(k2, k3));
    const float e0 = expf(k0 - m), e1 = expf(k1 - m),
                e2 = expf(k2 - m), e3 = expf(k3 - m);
    const float inv_s = 1.0f / (e0 + e1 + e2 + e3);
    // select this lane's strength without dynamic array indexing (rule #20)
    const float eb  = (b == 0) ? e0 : (b == 1) ? e1 : (b == 2) ? e2 : e3;
    const float fsb = 3.0f * eb * inv_s;

    // mexican hat constants
    const float v     = 0.75f + 1e-5f;
    const float inv_v = 1.0f / v;
    const float gs    = 1.0f / sqrtf(2.0f * 3.14159265358979323846f * v);

    const size_t tstride_x = (size_t)NB * CC * LL;
    const size_t tstride_o = (size_t)NB * KK * LL;
    const size_t base_x = ((size_t)n * CC + (size_t)kk * BB + b) * LL
                        + (size_t)l4 * 4;
    const size_t base_o = ((size_t)n * KK + kk) * LL + (size_t)l4 * 4;

    float pre[4];   // dendritic filter state for this compartment, 4 sites
    float h[4];     // somatic LIF state (redundant across b-lanes, exact)
    #pragma unroll
    for (int j = 0; j < 4; ++j) { pre[j] = 0.0f; h[j] = 0.0f; }

    float4 xv, xn;
    xv = *reinterpret_cast<const float4*>(x + base_x);

    #pragma unroll
    for (int t = 0; t < TT; ++t) {
        if (t + 1 < TT) {
            xn = *reinterpret_cast<const float4*>(
                     x + base_x + (size_t)(t + 1) * tstride_x);
        }

        const float xs[4] = { xv.x, xv.y, xv.z, xv.w };
        float y[4];
        #pragma unroll
        for (int j = 0; j < 4; ++j) {
            const float p = 0.5f * pre[j] + xs[j];      // alpha decay
            pre[j] = p;
            const float q = p * p * inv_v;
            const float g = expf(-0.5f * q) * gs;       // gaussian
            y[j] = fsb * ((1.0f - q) * g * inv_v);      // weighted mexican hat
        }

        // dendritic sum across compartments: (b0+b1)+(b2+b3) — same tree as
        // R2 (validated absmax 0.0); all lanes end with identical values.
        #pragma unroll
        for (int j = 0; j < 4; ++j) {
            y[j] += __shfl_xor(y[j], 16);
            y[j] += __shfl_xor(y[j], 32);
        }

        float4 o;
        float* op = &o.x;
        #pragma unroll
        for (int j = 0; j < 4; ++j) {
            const float hh = 0.5f * h[j] + y[j];            // beta decay
            const float s  = (hh - 1.0f >= 0.0f) ? 1.0f : 0.0f;  // heaviside
            h[j] = (s != 0.0f) ? 0.0f : hh;                 // hard reset
            op[j] = s;
        }
        if (b == 0)
            *reinterpret_cast<float4*>(out + base_o + (size_t)t * tstride_o) = o;

        xv = xn;
    }
}

extern "C" void kernel_launch(void* const* d_in, const int* in_sizes, int n_in,
                              void* d_out, int out_size, void* d_ws, size_t ws_size,
                              hipStream_t stream)
{
    const float* x = (const float*)d_in[0];
    const float* k = (const float*)d_in[1];
    float* out = (float*)d_out;

    // 524288 threads (4 per spatial 4-group, one per compartment)
    dendsn_fwd<<<2048, 256, 0, stream>>>(x, k, out);
}